// Round 9
// baseline (281.906 us; speedup 1.0000x reference)
//
#include <hip/hip_runtime.h>

#define NB 256
#define NS 197
#define ND 768
#define NDV4 192          // 768/4
#define ND2 384
#define ND4 192
#define NPOOL 50
#define PROMPT_FLOATS 40320   // 42*960
#define PROMPT_V4 10080
#define SCH 8             // S-chunks per batch
#define ROWS 25           // ceil(197/8)
#define PSLICE 1260       // PROMPT_V4 / SCH
#define TB 4              // batches per block in K2

// ---------------- K1: partial mean over S-chunk + prompt slice ----------------
// grid = NB*SCH = 2048 blocks x 192 threads (3 waves) => ~24 waves/CU.
// Each block: sums ROWS rows of one batch (thread = one float4 column, fully
// coalesced 3KB/step per wavegroup) and writes 1/8 of that batch's prompt copy
// so the broadcast write stream overlaps the x read stream.
__global__ __launch_bounds__(192) void k_partial(
    const float* __restrict__ x,        // [B,S,D]
    const float* __restrict__ prompt,   // [1,42,960]
    const int* __restrict__ layer_num,
    float* __restrict__ partial,        // ws [NB*SCH*ND]
    float* __restrict__ out_prompt)     // [B,40320]
{
    const int blk = blockIdx.x;
    const int b = blk >> 3;
    const int c = blk & 7;
    const int t = threadIdx.x;          // float4 column 0..191

    const float4* __restrict__ xr =
        reinterpret_cast<const float4*>(x) + (size_t)b * (NS * NDV4);
    const int s0 = c * ROWS;
    const int s1 = (s0 + ROWS < NS) ? (s0 + ROWS) : NS;
    float4 acc = make_float4(0.f, 0.f, 0.f, 0.f);
    for (int s = s0; s < s1; ++s) {
        float4 v = xr[(size_t)s * NDV4 + t];
        acc.x += v.x; acc.y += v.y; acc.z += v.z; acc.w += v.w;
    }
    reinterpret_cast<float4*>(partial)[(size_t)blk * NDV4 + t] = acc;

    // prompt slice c of batch b
    const float4* __restrict__ pv =
        reinterpret_cast<const float4*>(prompt + (size_t)layer_num[0] * PROMPT_FLOATS);
    float4* __restrict__ ov =
        reinterpret_cast<float4*>(out_prompt) + (size_t)b * PROMPT_V4;
    const int base = c * PSLICE;
    for (int i = t; i < PSLICE; i += 192) {
        ov[base + i] = pv[base + i];
    }
}

// ---------------- K2: reduce partials + MLP + l2norm + sim ----------------
// grid = NB/TB = 64 blocks x 512 threads. TB=4 batches/block gives 4x reuse of
// each W-row read (L2-resident weights). 32 groups x 16 lanes, coalesced
// W-rows, __shfl_xor butterfly K-reduction.
__global__ __launch_bounds__(512) void k_mlp(
    const float* __restrict__ partial,  // ws [NB*SCH*ND]
    const float* __restrict__ W1,       // [384,768]
    const float* __restrict__ b1,       // [384]
    const float* __restrict__ W2,       // [192,384]
    const float* __restrict__ b2,       // [192]
    const float* __restrict__ key,      // [50,192]
    float* __restrict__ sim,            // [B,50]
    float* __restrict__ xnorm)          // [B,192]
{
    const int tid = threadIdx.x;
    const int g   = tid >> 4;   // 0..31
    const int l   = tid & 15;
    const int b0  = blockIdx.x * TB;

    __shared__ __align__(16) float xm[TB][ND];    // 12 KB
    __shared__ __align__(16) float hs[TB][ND2];   // 6 KB
    __shared__ __align__(16) float fs[TB][ND4];   // 3 KB
    __shared__ float rs[TB];

    // ---- reduce SCH partials -> mean ----
    const float inv = 1.0f / (float)NS;
    for (int idx = tid; idx < TB * NDV4; idx += 512) {
        const int b = idx / NDV4, col = idx % NDV4;
        const float4* __restrict__ pr =
            reinterpret_cast<const float4*>(partial) +
            ((size_t)(b0 + b) * SCH) * NDV4 + col;
        float4 s = make_float4(0.f, 0.f, 0.f, 0.f);
        #pragma unroll
        for (int c = 0; c < SCH; ++c) {
            float4 v = pr[(size_t)c * NDV4];
            s.x += v.x; s.y += v.y; s.z += v.z; s.w += v.w;
        }
        reinterpret_cast<float4*>(&xm[b][0])[col] =
            make_float4(s.x * inv, s.y * inv, s.z * inv, s.w * inv);
    }
    __syncthreads();

    // ---- GEMM1: h = relu(xm @ W1^T + b1); 12 rows per group, 4 batches ----
    {
        const float4* __restrict__ x0v = reinterpret_cast<const float4*>(&xm[0][0]);
        const float4* __restrict__ x1v = reinterpret_cast<const float4*>(&xm[1][0]);
        const float4* __restrict__ x2v = reinterpret_cast<const float4*>(&xm[2][0]);
        const float4* __restrict__ x3v = reinterpret_cast<const float4*>(&xm[3][0]);
        for (int r = 0; r < ND2 / 32; ++r) {          // 12 rows per group
            const int i = g + 32 * r;
            const float4* __restrict__ w =
                reinterpret_cast<const float4*>(W1 + (size_t)i * ND);
            float a0 = 0.f, a1 = 0.f, a2 = 0.f, a3 = 0.f;
            #pragma unroll
            for (int s = 0; s < ND / 64; ++s) {       // 12 steps
                float4 wv = w[s * 16 + l];
                float4 x0 = x0v[s * 16 + l];
                float4 x1 = x1v[s * 16 + l];
                float4 x2 = x2v[s * 16 + l];
                float4 x3 = x3v[s * 16 + l];
                a0 += wv.x * x0.x + wv.y * x0.y + wv.z * x0.z + wv.w * x0.w;
                a1 += wv.x * x1.x + wv.y * x1.y + wv.z * x1.z + wv.w * x1.w;
                a2 += wv.x * x2.x + wv.y * x2.y + wv.z * x2.z + wv.w * x2.w;
                a3 += wv.x * x3.x + wv.y * x3.y + wv.z * x3.z + wv.w * x3.w;
            }
            #pragma unroll
            for (int m = 8; m; m >>= 1) {
                a0 += __shfl_xor(a0, m);
                a1 += __shfl_xor(a1, m);
                a2 += __shfl_xor(a2, m);
                a3 += __shfl_xor(a3, m);
            }
            if (l == 0) {
                const float bias = b1[i];
                hs[0][i] = fmaxf(a0 + bias, 0.f);
                hs[1][i] = fmaxf(a1 + bias, 0.f);
                hs[2][i] = fmaxf(a2 + bias, 0.f);
                hs[3][i] = fmaxf(a3 + bias, 0.f);
            }
        }
    }
    __syncthreads();

    // ---- GEMM2: f = h @ W2^T + b2; 6 rows per group, 4 batches ----
    {
        const float4* __restrict__ h0v = reinterpret_cast<const float4*>(&hs[0][0]);
        const float4* __restrict__ h1v = reinterpret_cast<const float4*>(&hs[1][0]);
        const float4* __restrict__ h2v = reinterpret_cast<const float4*>(&hs[2][0]);
        const float4* __restrict__ h3v = reinterpret_cast<const float4*>(&hs[3][0]);
        for (int r = 0; r < ND4 / 32; ++r) {          // 6 rows per group
            const int j = g + 32 * r;
            const float4* __restrict__ w =
                reinterpret_cast<const float4*>(W2 + (size_t)j * ND2);
            float a0 = 0.f, a1 = 0.f, a2 = 0.f, a3 = 0.f;
            #pragma unroll
            for (int s = 0; s < ND2 / 64; ++s) {      // 6 steps
                float4 wv = w[s * 16 + l];
                float4 h0 = h0v[s * 16 + l];
                float4 h1 = h1v[s * 16 + l];
                float4 h2 = h2v[s * 16 + l];
                float4 h3 = h3v[s * 16 + l];
                a0 += wv.x * h0.x + wv.y * h0.y + wv.z * h0.z + wv.w * h0.w;
                a1 += wv.x * h1.x + wv.y * h1.y + wv.z * h1.z + wv.w * h1.w;
                a2 += wv.x * h2.x + wv.y * h2.y + wv.z * h2.z + wv.w * h2.w;
                a3 += wv.x * h3.x + wv.y * h3.y + wv.z * h3.z + wv.w * h3.w;
            }
            #pragma unroll
            for (int m = 8; m; m >>= 1) {
                a0 += __shfl_xor(a0, m);
                a1 += __shfl_xor(a1, m);
                a2 += __shfl_xor(a2, m);
                a3 += __shfl_xor(a3, m);
            }
            if (l == 0) {
                const float bias = b2[j];
                fs[0][j] = a0 + bias;
                fs[1][j] = a1 + bias;
                fs[2][j] = a2 + bias;
                fs[3][j] = a3 + bias;
            }
        }
    }
    __syncthreads();

    // ---- per-batch squared norm: wave w -> batch w ----
    if (tid < TB * 64) {
        const int w = tid >> 6, ll = tid & 63;
        float v0 = fs[w][ll], v1 = fs[w][ll + 64], v2 = fs[w][ll + 128];
        float ss = v0 * v0 + v1 * v1 + v2 * v2;
        #pragma unroll
        for (int m = 32; m; m >>= 1) ss += __shfl_xor(ss, m);
        if (ll == 0) rs[w] = rsqrtf(fmaxf(ss, 1e-12f));
    }
    __syncthreads();

    // ---- normalize + write x_norm ----
    for (int idx = tid; idx < TB * ND4; idx += 512) {
        const int b = idx / ND4, j = idx - b * ND4;
        float v = fs[b][j] * rs[b];
        fs[b][j] = v;
        xnorm[(size_t)(b0 + b) * ND4 + j] = v;
    }
    __syncthreads();

    // ---- similarity: pool row per group ----
    {
        const float4* __restrict__ x0v = reinterpret_cast<const float4*>(&fs[0][0]);
        const float4* __restrict__ x1v = reinterpret_cast<const float4*>(&fs[1][0]);
        const float4* __restrict__ x2v = reinterpret_cast<const float4*>(&fs[2][0]);
        const float4* __restrict__ x3v = reinterpret_cast<const float4*>(&fs[3][0]);
        for (int p = g; p < NPOOL; p += 32) {
            const float4* __restrict__ kr =
                reinterpret_cast<const float4*>(key + (size_t)p * ND4);
            float kk = 0.f, d0 = 0.f, d1 = 0.f, d2 = 0.f, d3 = 0.f;
            #pragma unroll
            for (int s = 0; s < ND4 / 64; ++s) {      // 3 steps
                float4 kv = kr[s * 16 + l];
                float4 x0 = x0v[s * 16 + l];
                float4 x1 = x1v[s * 16 + l];
                float4 x2 = x2v[s * 16 + l];
                float4 x3 = x3v[s * 16 + l];
                kk += kv.x * kv.x + kv.y * kv.y + kv.z * kv.z + kv.w * kv.w;
                d0 += kv.x * x0.x + kv.y * x0.y + kv.z * x0.z + kv.w * x0.w;
                d1 += kv.x * x1.x + kv.y * x1.y + kv.z * x1.z + kv.w * x1.w;
                d2 += kv.x * x2.x + kv.y * x2.y + kv.z * x2.z + kv.w * x2.w;
                d3 += kv.x * x3.x + kv.y * x3.y + kv.z * x3.z + kv.w * x3.w;
            }
            #pragma unroll
            for (int m = 8; m; m >>= 1) {
                kk += __shfl_xor(kk, m);
                d0 += __shfl_xor(d0, m);
                d1 += __shfl_xor(d1, m);
                d2 += __shfl_xor(d2, m);
                d3 += __shfl_xor(d3, m);
            }
            if (l == 0) {
                const float krs = rsqrtf(fmaxf(kk, 1e-12f));
                sim[(size_t)(b0 + 0) * NPOOL + p] = d0 * krs;
                sim[(size_t)(b0 + 1) * NPOOL + p] = d1 * krs;
                sim[(size_t)(b0 + 2) * NPOOL + p] = d2 * krs;
                sim[(size_t)(b0 + 3) * NPOOL + p] = d3 * krs;
            }
        }
    }
}

extern "C" void kernel_launch(void* const* d_in, const int* in_sizes, int n_in,
                              void* d_out, int out_size, void* d_ws, size_t ws_size,
                              hipStream_t stream) {
    const float* x        = (const float*)d_in[0];  // [256,197,768]
    const float* prompt   = (const float*)d_in[1];  // [1,42,960]
    const float* key      = (const float*)d_in[2];  // [50,192]
    const float* W1       = (const float*)d_in[3];  // [384,768]
    const float* b1       = (const float*)d_in[4];  // [384]
    const float* W2       = (const float*)d_in[5];  // [192,384]
    const float* b2       = (const float*)d_in[6];  // [192]
    const int*   layer_nm = (const int*)d_in[7];    // scalar

    float* out        = (float*)d_out;
    float* sim        = out;                 // [256,50]
    float* xnorm      = out + 12800;         // [256,192]
    float* out_prompt = out + 12800 + 49152; // [256,40320]

    float* partial = (float*)d_ws;           // [256*8*768] = 6.3 MB

    hipLaunchKernelGGL(k_partial, dim3(NB * SCH), dim3(192), 0, stream,
                       x, prompt, layer_nm, partial, out_prompt);
    hipLaunchKernelGGL(k_mlp, dim3(NB / TB), dim3(512), 0, stream,
                       partial, W1, b1, W2, b2, key, sim, xnorm);
}